// Round 1
// baseline (582.139 us; speedup 1.0000x reference)
//
#include <hip/hip_runtime.h>

#define B_ 8
#define C_ 19
#define H_ 512
#define W_ 512
#define HW_ (H_*W_)

typedef unsigned long long u64;

// horizontal 3-wide spread (incl. center) of a 64-pixel word, with carries
__device__ __forceinline__ u64 hsp(u64 cc, u64 ll, u64 rr) {
    return cc | (cc << 1) | (ll >> 63) | (cc >> 1) | (rr << 63);
}

// One block per (b,c) image. Bit-packed masks in LDS: 512 rows x 8 u64 words.
// sdf(p) = first step at which the 3x3-box dilation covers p (capped 20),
// with step-1 specialized to the exclude-center kernel + isolated-pixel fix.
__global__ __launch_bounds__(1024) void sdf_kernel(const int* __restrict__ target,
                                                   unsigned char* __restrict__ sdf) {
    __shared__ u64 bufA[4096];
    __shared__ u64 bufB[4096];
    const int bc = blockIdx.x;           // 0..151
    const int b  = bc / C_;
    const int c  = bc - b * C_;
    const int tid = threadIdx.x;
    const int* tgt = target + b * HW_;
    unsigned char* out = sdf + (size_t)bc * HW_;

    // ---- build S bit-packed: wave-aligned ballot -> one u64 per 64 pixels
    #pragma unroll 4
    for (int p = tid; p < HW_; p += 1024) {
        u64 m = __ballot(tgt[p] == c);
        if ((tid & 63) == 0) bufA[p >> 6] = m;
    }
    __syncthreads();

    u64* cur = bufA;
    u64* nxt = bufB;

    // ---- step 1: neighbor-OR excluding center (row uses only left/right)
    for (int k = 0; k < 4; ++k) {
        const int idx = tid + k * 1024;
        const int r = idx >> 3, w = idx & 7;
        u64 cc = cur[idx];
        u64 ll = w        ? cur[idx-1] : 0;
        u64 rr = (w < 7)  ? cur[idx+1] : 0;
        u64 uc=0, ul=0, ur=0, dc=0, dl=0, dr=0;
        if (r > 0)   { uc = cur[idx-8]; ul = w ? cur[idx-9] : 0; ur = (w<7) ? cur[idx-7] : 0; }
        if (r < 511) { dc = cur[idx+8]; dl = w ? cur[idx+7] : 0; dr = (w<7) ? cur[idx+9] : 0; }
        u64 nbr = ((cc<<1)|(ll>>63)) | ((cc>>1)|(rr<<63)) | hsp(uc,ul,ur) | hsp(dc,dl,dr);
        nxt[idx] = cc | nbr;            // M_1
        const int basep = r * W_ + w * 64;
        u64 zb = cc & nbr;              // foreground w/ neighbor -> 0
        u64 ob = cc ^ nbr;              // isolated fg OR first reached -> 1
        while (zb) { int i = __builtin_ctzll(zb); out[basep + i] = 0; zb &= zb - 1; }
        while (ob) { int i = __builtin_ctzll(ob); out[basep + i] = 1; ob &= ob - 1; }
    }
    cur = bufB; nxt = bufA;

    // ---- steps 2..19: full 3x3 box dilation; newly set bits get value=step
    for (int step = 2; step <= 19; ++step) {
        __syncthreads();
        for (int k = 0; k < 4; ++k) {
            const int idx = tid + k * 1024;
            const int r = idx >> 3, w = idx & 7;
            u64 cc = cur[idx];
            u64 ll = w        ? cur[idx-1] : 0;
            u64 rr = (w < 7)  ? cur[idx+1] : 0;
            u64 uc=0, ul=0, ur=0, dc=0, dl=0, dr=0;
            if (r > 0)   { uc = cur[idx-8]; ul = w ? cur[idx-9] : 0; ur = (w<7) ? cur[idx-7] : 0; }
            if (r < 511) { dc = cur[idx+8]; dl = w ? cur[idx+7] : 0; dr = (w<7) ? cur[idx+9] : 0; }
            u64 d = hsp(cc,ll,rr) | hsp(uc,ul,ur) | hsp(dc,dl,dr);
            u64 nb = d & ~cc;
            nxt[idx] = d;
            const int basep = r * W_ + w * 64;
            while (nb) { int i = __builtin_ctzll(nb); out[basep + i] = (unsigned char)step; nb &= nb - 1; }
        }
        u64* t = cur; cur = nxt; nxt = t;
    }
    __syncthreads();

    // ---- never covered within 19 steps -> 20 (covers both d==20 and d>20)
    for (int k = 0; k < 4; ++k) {
        const int idx = tid + k * 1024;
        const int r = idx >> 3, w = idx & 7;
        u64 rem = ~cur[idx];
        const int basep = r * W_ + w * 64;
        while (rem) { int i = __builtin_ctzll(rem); out[basep + i] = 20; rem &= rem - 1; }
    }
}

// mean(softmax(pred, axis=C) * sdf); 4 pixels per thread via float4/uchar4.
__global__ __launch_bounds__(256) void loss_kernel(const float* __restrict__ pred,
                                                   const unsigned char* __restrict__ sdf,
                                                   float* __restrict__ out) {
    const int t = blockIdx.x * 256 + threadIdx.x;   // 0..524287
    const int b = t >> 16;                          // 65536 threads per batch image
    const int hw4 = (t & 65535) << 2;
    const float*         pbase = pred + (size_t)b * C_ * HW_ + hw4;
    const unsigned char* sbase = sdf  + (size_t)b * C_ * HW_ + hw4;
    float se0=0.f, se1=0.f, se2=0.f, se3=0.f;
    float d0=0.f, d1=0.f, d2=0.f, d3=0.f;
    #pragma unroll
    for (int c = 0; c < C_; ++c) {
        float4 v = *(const float4*)(pbase + (size_t)c * HW_);
        uchar4 s = *(const uchar4*)(sbase + (size_t)c * HW_);
        float e0 = __expf(v.x), e1 = __expf(v.y), e2 = __expf(v.z), e3 = __expf(v.w);
        se0 += e0; se1 += e1; se2 += e2; se3 += e3;
        d0 += e0 * (float)s.x; d1 += e1 * (float)s.y;
        d2 += e2 * (float)s.z; d3 += e3 * (float)s.w;
    }
    float local = d0/se0 + d1/se1 + d2/se2 + d3/se3;
    #pragma unroll
    for (int off = 32; off > 0; off >>= 1) local += __shfl_down(local, off);
    __shared__ float part[4];
    if ((threadIdx.x & 63) == 0) part[threadIdx.x >> 6] = local;
    __syncthreads();
    if (threadIdx.x == 0) {
        float s = (part[0] + part[1]) + (part[2] + part[3]);
        atomicAdd(out, s * (1.0f / 39845888.0f));   // / (B*C*H*W)
    }
}

extern "C" void kernel_launch(void* const* d_in, const int* in_sizes, int n_in,
                              void* d_out, int out_size, void* d_ws, size_t ws_size,
                              hipStream_t stream) {
    const float* pred   = (const float*)d_in[0];
    const int*   target = (const int*)d_in[1];
    unsigned char* sdf  = (unsigned char*)d_ws;       // B*C*H*W = 39,845,888 bytes
    float* out = (float*)d_out;

    hipMemsetAsync(out, 0, sizeof(float), stream);    // harness poisons d_out
    sdf_kernel<<<B_ * C_, 1024, 0, stream>>>(target, sdf);
    loss_kernel<<<2048, 256, 0, stream>>>(pred, sdf, out);
}

// Round 2
// 371.560 us; speedup vs baseline: 1.5667x; 1.5667x over previous
//
#include <hip/hip_runtime.h>

#define B_ 8
#define C_ 19
#define H_ 512
#define W_ 512
#define HW_ (H_*W_)

typedef unsigned long long u64;

// One block per (b,c) image. Bit-packed masks in LDS (512 rows x 8 u64 words,
// double-buffered = 64KB). Each thread owns 4 stacked rows of one word-column;
// per-pixel sdf value accumulated as 5 bit-planes in registers:
//   value = #steps s in 0..19 with pixel uncovered  (+1 if isolated fg)
// Early-exit when dilation converges; remaining steps added in closed form.
__global__ __launch_bounds__(1024) void sdf_kernel(const int* __restrict__ target,
                                                   unsigned char* __restrict__ sdf) {
    __shared__ u64 bufA[4096];
    __shared__ u64 bufB[4096];
    __shared__ int chg[2];
    const int bc = blockIdx.x;           // 0..151
    const int b  = bc / C_;
    const int c  = bc - b * C_;
    const int tid = threadIdx.x;
    const int* tgt = target + b * HW_;
    unsigned char* out = sdf + (size_t)bc * HW_;

    if (tid < 2) chg[tid] = 0;

    // ---- build S bit-packed via wave ballot (word q = pixels q*64..q*64+63)
    {
        const int lane = tid & 63, wv = tid >> 6;
        for (int q = wv; q < 4096; q += 16) {
            u64 m = __ballot(tgt[(q << 6) + lane] == c);
            if (lane == 0) bufA[q] = m;
        }
    }
    __syncthreads();

    const int w  = tid & 7;        // word column 0..7
    const int r0 = (tid >> 3) * 4; // first owned row (4 stacked rows)

    u64 cnt[4][5];                 // 5-bit counters per owned word
    u64 iso[4];                    // isolated-fg bits
    u64 save[4];                   // last dilation result per owned word
    #pragma unroll
    for (int i = 0; i < 4; ++i) {
        iso[i] = 0; save[i] = 0;
        #pragma unroll
        for (int j = 0; j < 5; ++j) cnt[i][j] = 0;
    }

    u64* cur = bufA;
    u64* nxt = bufB;
    int  Kleft;
    bool conv = false;

    // ---- step 1: exclude-center neighbor OR (for iso detection), then union
    {
        u64 h[6], nc[6], ccm[6];
        #pragma unroll
        for (int j = 0; j < 6; ++j) {
            const int r = r0 - 1 + j;
            u64 C = 0, L = 0, R = 0;
            if (r >= 0 && r < 512) {
                const u64* p = cur + r * 8 + w;
                C = p[0];
                L = w ? p[-1] : 0;
                R = (w < 7) ? p[1] : 0;
            }
            nc[j]  = (C << 1) | (L >> 63) | (C >> 1) | (R << 63);
            h[j]   = nc[j] | C;
            ccm[j] = C;
        }
        u64 diff = 0;
        #pragma unroll
        for (int i = 0; i < 4; ++i) {
            const u64 cc  = ccm[i + 1];
            const u64 nbr = nc[i + 1] | h[i] | h[i + 2];
            const u64 d   = cc | nbr;
            iso[i] = cc & ~nbr;
            diff |= d ^ cc;
            u64 carry = ~cc;                     // count step 0 uncovered
            #pragma unroll
            for (int j = 0; j < 5; ++j) { u64 t = cnt[i][j] & carry; cnt[i][j] ^= carry; carry = t; }
            save[i] = d;
            nxt[(r0 + i) * 8 + w] = d;
        }
        if (diff) chg[1] = 1;
        if (tid == 0) chg[0] = 0;
        __syncthreads();
        if (!chg[1]) { Kleft = 19; conv = true; }
        else { u64* t = cur; cur = nxt; nxt = t; }
    }

    // ---- steps 2..19: full 3x3 box dilation with early exit
    if (!conv) {
        for (int s = 2; s <= 19; ++s) {
            u64 h[6], ccm[4];
            #pragma unroll
            for (int j = 0; j < 6; ++j) {
                const int r = r0 - 1 + j;
                u64 C = 0, L = 0, R = 0;
                if (r >= 0 && r < 512) {
                    const u64* p = cur + r * 8 + w;
                    C = p[0];
                    L = w ? p[-1] : 0;
                    R = (w < 7) ? p[1] : 0;
                }
                h[j] = C | (C << 1) | (L >> 63) | (C >> 1) | (R << 63);
                if (j >= 1 && j <= 4) ccm[j - 1] = C;
            }
            u64 diff = 0;
            #pragma unroll
            for (int i = 0; i < 4; ++i) {
                const u64 cc = ccm[i];
                const u64 d  = h[i] | h[i + 1] | h[i + 2];
                diff |= d ^ cc;
                u64 carry = ~cc;                 // count step s-1 uncovered
                #pragma unroll
                for (int j = 0; j < 5; ++j) { u64 t = cnt[i][j] & carry; cnt[i][j] ^= carry; carry = t; }
                save[i] = d;
                nxt[(r0 + i) * 8 + w] = d;
            }
            if (diff) chg[s & 1] = 1;
            if (tid == 0) chg[(s + 1) & 1] = 0;
            __syncthreads();
            if (!chg[s & 1]) { Kleft = 20 - s; conv = true; break; }
            u64* t = cur; cur = nxt; nxt = t;
        }
        if (!conv) Kleft = 1;                    // one more inc with ~cov_19
    }

    // ---- add remaining Kleft increments in closed form (mask = still uncovered)
    #pragma unroll
    for (int i = 0; i < 4; ++i) {
        const u64 m = ~save[i];
        u64 carry = 0;
        #pragma unroll
        for (int j = 0; j < 5; ++j) {
            const u64 a  = ((Kleft >> j) & 1) ? m : 0;
            const u64 x  = cnt[i][j];
            const u64 s1 = x ^ a;
            const u64 c1 = x & a;
            cnt[i][j] = s1 ^ carry;
            carry = c1 | (s1 & carry);
        }
    }

    // ---- 8x8 bit transpose planes -> bytes; coalesced 16B stores
    #pragma unroll
    for (int i = 0; i < 4; ++i) {
        cnt[i][0] |= iso[i];                     // isolated fg: 0 -> 1
        unsigned char* base = out + (r0 + i) * 512 + w * 64;
        union { u64 q[8]; uint4 v[4]; } o;
        #pragma unroll
        for (int g = 0; g < 8; ++g) {
            u64 x = 0;
            #pragma unroll
            for (int j = 0; j < 5; ++j)
                x |= ((cnt[i][j] >> (8 * g)) & 0xFFULL) << (8 * j);
            u64 t;
            t = (x ^ (x >> 7))  & 0x00AA00AA00AA00AAULL; x ^= t ^ (t << 7);
            t = (x ^ (x >> 14)) & 0x0000CCCC0000CCCCULL; x ^= t ^ (t << 14);
            t = (x ^ (x >> 28)) & 0x00000000F0F0F0F0ULL; x ^= t ^ (t << 28);
            o.q[g] = x;
        }
        #pragma unroll
        for (int k = 0; k < 4; ++k) ((uint4*)base)[k] = o.v[k];
    }
}

// mean(softmax(pred, axis=C) * sdf); 4 pixels per thread via float4/uchar4.
__global__ __launch_bounds__(256) void loss_kernel(const float* __restrict__ pred,
                                                   const unsigned char* __restrict__ sdf,
                                                   float* __restrict__ out) {
    const int t = blockIdx.x * 256 + threadIdx.x;   // 0..524287
    const int b = t >> 16;                          // 65536 threads per batch image
    const int hw4 = (t & 65535) << 2;
    const float*         pbase = pred + (size_t)b * C_ * HW_ + hw4;
    const unsigned char* sbase = sdf  + (size_t)b * C_ * HW_ + hw4;
    float se0=0.f, se1=0.f, se2=0.f, se3=0.f;
    float d0=0.f, d1=0.f, d2=0.f, d3=0.f;
    #pragma unroll
    for (int c = 0; c < C_; ++c) {
        float4 v = *(const float4*)(pbase + (size_t)c * HW_);
        uchar4 s = *(const uchar4*)(sbase + (size_t)c * HW_);
        float e0 = __expf(v.x), e1 = __expf(v.y), e2 = __expf(v.z), e3 = __expf(v.w);
        se0 += e0; se1 += e1; se2 += e2; se3 += e3;
        d0 += e0 * (float)s.x; d1 += e1 * (float)s.y;
        d2 += e2 * (float)s.z; d3 += e3 * (float)s.w;
    }
    float local = d0/se0 + d1/se1 + d2/se2 + d3/se3;
    #pragma unroll
    for (int off = 32; off > 0; off >>= 1) local += __shfl_down(local, off);
    __shared__ float part[4];
    if ((threadIdx.x & 63) == 0) part[threadIdx.x >> 6] = local;
    __syncthreads();
    if (threadIdx.x == 0) {
        float s = (part[0] + part[1]) + (part[2] + part[3]);
        atomicAdd(out, s * (1.0f / 39845888.0f));   // / (B*C*H*W)
    }
}

extern "C" void kernel_launch(void* const* d_in, const int* in_sizes, int n_in,
                              void* d_out, int out_size, void* d_ws, size_t ws_size,
                              hipStream_t stream) {
    const float* pred   = (const float*)d_in[0];
    const int*   target = (const int*)d_in[1];
    unsigned char* sdf  = (unsigned char*)d_ws;       // B*C*H*W = 39,845,888 bytes
    float* out = (float*)d_out;

    hipMemsetAsync(out, 0, sizeof(float), stream);    // harness poisons d_out
    sdf_kernel<<<B_ * C_, 1024, 0, stream>>>(target, sdf);
    loss_kernel<<<2048, 256, 0, stream>>>(pred, sdf, out);
}

// Round 3
// 357.800 us; speedup vs baseline: 1.6270x; 1.0385x over previous
//
#include <hip/hip_runtime.h>

#define B_ 8
#define C_ 19
#define H_ 512
#define W_ 512
#define HW_ (H_*W_)

#define HALO   20
#define SINT   88            // interior rows per strip
#define SROWS  128           // HALO + SINT + HALO
#define NSTRIP 6             // 6*88 = 528 >= 512
#define LSTR   9             // padded LDS row stride in u64 (bank de-alias)

typedef unsigned long long u64;

// One block per (b,c,strip): 128-row window (88 interior + 20 halo each side).
// Bit-packed masks in LDS (stride-9 u64 rows, double buffered ~18KB). Thread
// owns 4 stacked rows of one word-column; sdf accumulated as 5 bit-planes:
//   value = #steps s in 0..19 with pixel uncovered  (+1 if isolated fg)
// Early-exit on local convergence; remaining steps added in closed form.
__global__ __launch_bounds__(256) void sdf_kernel(const int* __restrict__ target,
                                                  unsigned char* __restrict__ sdf) {
    __shared__ u64 bufA[SROWS * LSTR];
    __shared__ u64 bufB[SROWS * LSTR];
    __shared__ int chg[2];
    const int blk   = blockIdx.x;            // 0 .. 8*19*6-1
    const int strip = blk % NSTRIP;
    const int bc    = blk / NSTRIP;
    const int b     = bc / C_;
    const int c     = bc - b * C_;
    const int y0    = strip * SINT;          // first interior global row
    const int tid   = threadIdx.x;
    const int* tgt  = target + b * HW_;
    unsigned char* out = sdf + (size_t)bc * HW_;

    if (tid < 2) chg[tid] = 0;

    // ---- build S bit-packed via wave ballot; rows outside image -> 0
    {
        const int lane = tid & 63, wv = tid >> 6;
        #pragma unroll 4
        for (int q = wv; q < SROWS * 8; q += 4) {
            const int lr = q >> 3, wq = q & 7;
            const int gy = y0 - HALO + lr;
            u64 m = 0;
            if (gy >= 0 && gy < H_)
                m = __ballot(tgt[(gy << 9) + (wq << 6) + lane] == c);
            if (lane == 0) bufA[lr * LSTR + wq] = m;
        }
    }
    __syncthreads();

    const int w  = tid & 7;        // word column 0..7
    const int r0 = (tid >> 3) * 4; // first owned local row (4 stacked rows)

    u64 cnt[4][5];                 // 5-bit counters per owned word
    u64 iso[4];                    // isolated-fg bits
    u64 save[4];                   // last dilation result per owned word
    #pragma unroll
    for (int i = 0; i < 4; ++i) {
        iso[i] = 0; save[i] = 0;
        #pragma unroll
        for (int j = 0; j < 5; ++j) cnt[i][j] = 0;
    }

    u64* cur = bufA;
    u64* nxt = bufB;
    int  Kleft;
    bool conv = false;

    // ---- step 1: exclude-center neighbor OR (for iso), then union
    {
        u64 h[6], nc[6], ccm[6];
        #pragma unroll
        for (int j = 0; j < 6; ++j) {
            const int r = r0 - 1 + j;
            u64 C = 0, L = 0, R = 0;
            if (r >= 0 && r < SROWS) {
                const u64* p = cur + r * LSTR + w;
                C = p[0];
                L = w ? p[-1] : 0;
                R = (w < 7) ? p[1] : 0;
            }
            nc[j]  = (C << 1) | (L >> 63) | (C >> 1) | (R << 63);
            h[j]   = nc[j] | C;
            ccm[j] = C;
        }
        u64 diff = 0;
        #pragma unroll
        for (int i = 0; i < 4; ++i) {
            const u64 cc  = ccm[i + 1];
            const u64 nbr = nc[i + 1] | h[i] | h[i + 2];
            const u64 d   = cc | nbr;
            iso[i] = cc & ~nbr;
            diff |= d ^ cc;
            u64 carry = ~cc;                     // count step 0 uncovered
            #pragma unroll
            for (int j = 0; j < 5; ++j) { u64 t = cnt[i][j] & carry; cnt[i][j] ^= carry; carry = t; }
            save[i] = d;
            nxt[(r0 + i) * LSTR + w] = d;
        }
        if (diff) chg[1] = 1;
        if (tid == 0) chg[0] = 0;
        __syncthreads();
        if (!chg[1]) { Kleft = 19; conv = true; }
        else { u64* t = cur; cur = nxt; nxt = t; }
    }

    // ---- steps 2..19: full 3x3 box dilation with early exit
    if (!conv) {
        for (int s = 2; s <= 19; ++s) {
            u64 h[6], ccm[4];
            #pragma unroll
            for (int j = 0; j < 6; ++j) {
                const int r = r0 - 1 + j;
                u64 C = 0, L = 0, R = 0;
                if (r >= 0 && r < SROWS) {
                    const u64* p = cur + r * LSTR + w;
                    C = p[0];
                    L = w ? p[-1] : 0;
                    R = (w < 7) ? p[1] : 0;
                }
                h[j] = C | (C << 1) | (L >> 63) | (C >> 1) | (R << 63);
                if (j >= 1 && j <= 4) ccm[j - 1] = C;
            }
            u64 diff = 0;
            #pragma unroll
            for (int i = 0; i < 4; ++i) {
                const u64 cc = ccm[i];
                const u64 d  = h[i] | h[i + 1] | h[i + 2];
                diff |= d ^ cc;
                u64 carry = ~cc;                 // count step s-1 uncovered
                #pragma unroll
                for (int j = 0; j < 5; ++j) { u64 t = cnt[i][j] & carry; cnt[i][j] ^= carry; carry = t; }
                save[i] = d;
                nxt[(r0 + i) * LSTR + w] = d;
            }
            if (diff) chg[s & 1] = 1;
            if (tid == 0) chg[(s + 1) & 1] = 0;
            __syncthreads();
            if (!chg[s & 1]) { Kleft = 20 - s; conv = true; break; }
            u64* t = cur; cur = nxt; nxt = t;
        }
        if (!conv) Kleft = 1;                    // one more inc with ~cov_19
    }

    // ---- add remaining Kleft increments in closed form (mask = uncovered)
    #pragma unroll
    for (int i = 0; i < 4; ++i) {
        const u64 m = ~save[i];
        u64 carry = 0;
        #pragma unroll
        for (int j = 0; j < 5; ++j) {
            const u64 a  = ((Kleft >> j) & 1) ? m : 0;
            const u64 x  = cnt[i][j];
            const u64 s1 = x ^ a;
            const u64 c1 = x & a;
            cnt[i][j] = s1 ^ carry;
            carry = c1 | (s1 & carry);
        }
    }

    // ---- 8x8 bit transpose planes -> bytes; store interior rows only
    #pragma unroll
    for (int i = 0; i < 4; ++i) {
        const int lr = r0 + i;
        const int gy = y0 - HALO + lr;
        if (lr < HALO || lr >= HALO + SINT || gy >= H_) continue;
        cnt[i][0] |= iso[i];                     // isolated fg: 0 -> 1
        unsigned char* base = out + gy * W_ + w * 64;
        union { u64 q[8]; uint4 v[4]; } o;
        #pragma unroll
        for (int g = 0; g < 8; ++g) {
            u64 x = 0;
            #pragma unroll
            for (int j = 0; j < 5; ++j)
                x |= ((cnt[i][j] >> (8 * g)) & 0xFFULL) << (8 * j);
            u64 t;
            t = (x ^ (x >> 7))  & 0x00AA00AA00AA00AAULL; x ^= t ^ (t << 7);
            t = (x ^ (x >> 14)) & 0x0000CCCC0000CCCCULL; x ^= t ^ (t << 14);
            t = (x ^ (x >> 28)) & 0x00000000F0F0F0F0ULL; x ^= t ^ (t << 28);
            o.q[g] = x;
        }
        #pragma unroll
        for (int k = 0; k < 4; ++k) ((uint4*)base)[k] = o.v[k];
    }
}

// mean(softmax(pred, axis=C) * sdf); 4 pixels per thread via float4/uchar4.
__global__ __launch_bounds__(256) void loss_kernel(const float* __restrict__ pred,
                                                   const unsigned char* __restrict__ sdf,
                                                   float* __restrict__ out) {
    const int t = blockIdx.x * 256 + threadIdx.x;   // 0..524287
    const int b = t >> 16;                          // 65536 threads per batch image
    const int hw4 = (t & 65535) << 2;
    const float*         pbase = pred + (size_t)b * C_ * HW_ + hw4;
    const unsigned char* sbase = sdf  + (size_t)b * C_ * HW_ + hw4;
    float se0=0.f, se1=0.f, se2=0.f, se3=0.f;
    float d0=0.f, d1=0.f, d2=0.f, d3=0.f;
    #pragma unroll
    for (int c = 0; c < C_; ++c) {
        float4 v = *(const float4*)(pbase + (size_t)c * HW_);
        uchar4 s = *(const uchar4*)(sbase + (size_t)c * HW_);
        float e0 = __expf(v.x), e1 = __expf(v.y), e2 = __expf(v.z), e3 = __expf(v.w);
        se0 += e0; se1 += e1; se2 += e2; se3 += e3;
        d0 += e0 * (float)s.x; d1 += e1 * (float)s.y;
        d2 += e2 * (float)s.z; d3 += e3 * (float)s.w;
    }
    float local = d0/se0 + d1/se1 + d2/se2 + d3/se3;
    #pragma unroll
    for (int off = 32; off > 0; off >>= 1) local += __shfl_down(local, off);
    __shared__ float part[4];
    if ((threadIdx.x & 63) == 0) part[threadIdx.x >> 6] = local;
    __syncthreads();
    if (threadIdx.x == 0) {
        float s = (part[0] + part[1]) + (part[2] + part[3]);
        atomicAdd(out, s * (1.0f / 39845888.0f));   // / (B*C*H*W)
    }
}

extern "C" void kernel_launch(void* const* d_in, const int* in_sizes, int n_in,
                              void* d_out, int out_size, void* d_ws, size_t ws_size,
                              hipStream_t stream) {
    const float* pred   = (const float*)d_in[0];
    const int*   target = (const int*)d_in[1];
    unsigned char* sdf  = (unsigned char*)d_ws;       // B*C*H*W = 39,845,888 bytes
    float* out = (float*)d_out;

    hipMemsetAsync(out, 0, sizeof(float), stream);    // harness poisons d_out
    sdf_kernel<<<B_ * C_ * NSTRIP, 256, 0, stream>>>(target, sdf);
    loss_kernel<<<2048, 256, 0, stream>>>(pred, sdf, out);
}

// Round 4
// 325.862 us; speedup vs baseline: 1.7865x; 1.0980x over previous
//
#include <hip/hip_runtime.h>

#define B_ 8
#define C_ 19
#define H_ 512
#define W_ 512
#define HW_ (H_*W_)

#define HALO   20
#define SINT   56            // interior rows per strip
#define SROWS  96            // HALO + SINT + HALO
#define NSTRIP 10            // 10*56 = 560 >= 512
#define LSTR   9             // padded LDS row stride in u64

typedef unsigned long long u64;

// ---------- pass A: bit-pack target into per-class masks (once, not 19x) ----
// masks[b][c][q] : u64, bit i = (target[b][q*64+i] == c)
__global__ __launch_bounds__(256) void mask_kernel(const int* __restrict__ target,
                                                   u64* __restrict__ masks) {
    __shared__ u64 mlds[128][21];
    const int blk  = blockIdx.x;          // 256 blocks, 32 per image
    const int b    = blk >> 5;
    const int base = (blk & 31) * 128;    // first word within image
    const int tid  = threadIdx.x;
    const int lane = tid & 63, wv = tid >> 6;
    const int* tgt = target + b * HW_;
    for (int t = 0; t < 32; ++t) {
        const int cl = wv * 32 + t;       // chunk local 0..127
        const int x  = tgt[(base + cl) * 64 + lane];
        u64 keep = 0;
        #pragma unroll
        for (int c = 0; c < C_; ++c) {
            u64 m = __ballot(x == c);
            if (lane == c) keep = m;
        }
        if (lane < C_) mlds[cl][lane] = keep;
    }
    __syncthreads();
    for (int idx = tid; idx < C_ * 128; idx += 256) {
        const int c = idx >> 7, wl = idx & 127;
        masks[((size_t)b * C_ + c) * 4096 + base + wl] = mlds[wl][c];
    }
}

// ---------- pass B: inverse softmax denominator per pixel --------------------
__global__ __launch_bounds__(256) void invd_kernel(const float* __restrict__ pred,
                                                   float* __restrict__ invd) {
    const int t   = blockIdx.x * 256 + threadIdx.x;   // 0..524287
    const int b   = t >> 16;
    const int hw4 = (t & 65535) << 2;
    const float* pbase = pred + (size_t)b * C_ * HW_ + hw4;
    float s0=0.f, s1=0.f, s2=0.f, s3=0.f;
    #pragma unroll
    for (int c = 0; c < C_; ++c) {
        float4 v = *(const float4*)(pbase + (size_t)c * HW_);
        s0 += __expf(v.x); s1 += __expf(v.y); s2 += __expf(v.z); s3 += __expf(v.w);
    }
    float4 o; o.x = 1.0f/s0; o.y = 1.0f/s1; o.z = 1.0f/s2; o.w = 1.0f/s3;
    *(float4*)(invd + (size_t)b * HW_ + hw4) = o;
}

// ---------- pass C: strip dilation counters + fused loss ---------------------
// One block per (b,c,strip): 96-row window (56 interior + 20 halo each side).
// Thread owns 3 stacked rows of one 64-px word column; sdf as 5 bit-planes:
//   value = #steps s in 0..19 with pixel uncovered (+1 if isolated fg)
// Epilogue: planes -> bytes, acc += expf(pred)*invd*value, block atomicAdd.
__global__ __launch_bounds__(256) void sdf_loss_kernel(const u64* __restrict__ masks,
                                                       const float* __restrict__ pred,
                                                       const float* __restrict__ invd,
                                                       float* __restrict__ out) {
    __shared__ u64 bufA[SROWS * LSTR];
    __shared__ u64 bufB[SROWS * LSTR];
    __shared__ int chg[2];
    __shared__ float part[4];
    const int blk   = blockIdx.x;            // 0 .. 8*19*10-1
    const int strip = blk % NSTRIP;
    const int bc    = blk / NSTRIP;
    const int b     = bc / C_;
    const int c     = bc - b * C_;
    const int y0    = strip * SINT;          // first interior global row
    const int tid   = threadIdx.x;
    const u64* mk   = masks + ((size_t)b * C_ + c) * 4096;

    if (tid < 2) chg[tid] = 0;

    // build window from pre-packed masks (3 coalesced u64 loads per thread)
    for (int idx = tid; idx < SROWS * 8; idx += 256) {
        const int lr = idx >> 3, wq = idx & 7;
        const int gy = y0 - HALO + lr;
        u64 m = 0;
        if (gy >= 0 && gy < H_) m = mk[gy * 8 + wq];
        bufA[lr * LSTR + wq] = m;
    }
    __syncthreads();

    const int w  = tid & 7;        // word column 0..7
    const int r0 = (tid >> 3) * 3; // first owned local row (3 stacked rows)

    u64 cnt[3][5];                 // 5-bit counters per owned word
    u64 iso[3];                    // isolated-fg bits
    u64 save[3];                   // last dilation result per owned word
    #pragma unroll
    for (int i = 0; i < 3; ++i) {
        iso[i] = 0; save[i] = 0;
        #pragma unroll
        for (int j = 0; j < 5; ++j) cnt[i][j] = 0;
    }

    u64* cur = bufA;
    u64* nxt = bufB;
    int  Kleft;
    bool conv = false;

    // ---- step 1: exclude-center neighbor OR (for iso), then union
    {
        u64 h[5], nc[5], ccm[5];
        #pragma unroll
        for (int j = 0; j < 5; ++j) {
            const int r = r0 - 1 + j;
            u64 C = 0, L = 0, R = 0;
            if (r >= 0 && r < SROWS) {
                const u64* p = cur + r * LSTR + w;
                C = p[0];
                L = w ? p[-1] : 0;
                R = (w < 7) ? p[1] : 0;
            }
            nc[j]  = (C << 1) | (L >> 63) | (C >> 1) | (R << 63);
            h[j]   = nc[j] | C;
            ccm[j] = C;
        }
        u64 diff = 0;
        #pragma unroll
        for (int i = 0; i < 3; ++i) {
            const u64 cc  = ccm[i + 1];
            const u64 nbr = nc[i + 1] | h[i] | h[i + 2];
            const u64 d   = cc | nbr;
            iso[i] = cc & ~nbr;
            diff |= d ^ cc;
            u64 carry = ~cc;                     // count step 0 uncovered
            #pragma unroll
            for (int j = 0; j < 5; ++j) { u64 t = cnt[i][j] & carry; cnt[i][j] ^= carry; carry = t; }
            save[i] = d;
            nxt[(r0 + i) * LSTR + w] = d;
        }
        if (diff) chg[1] = 1;
        if (tid == 0) chg[0] = 0;
        __syncthreads();
        if (!chg[1]) { Kleft = 19; conv = true; }
        else { u64* t = cur; cur = nxt; nxt = t; }
    }

    // ---- steps 2..19: full 3x3 box dilation with early exit
    if (!conv) {
        for (int s = 2; s <= 19; ++s) {
            u64 h[5], ccm[3];
            #pragma unroll
            for (int j = 0; j < 5; ++j) {
                const int r = r0 - 1 + j;
                u64 C = 0, L = 0, R = 0;
                if (r >= 0 && r < SROWS) {
                    const u64* p = cur + r * LSTR + w;
                    C = p[0];
                    L = w ? p[-1] : 0;
                    R = (w < 7) ? p[1] : 0;
                }
                h[j] = C | (C << 1) | (L >> 63) | (C >> 1) | (R << 63);
                if (j >= 1 && j <= 3) ccm[j - 1] = C;
            }
            u64 diff = 0;
            #pragma unroll
            for (int i = 0; i < 3; ++i) {
                const u64 cc = ccm[i];
                const u64 d  = h[i] | h[i + 1] | h[i + 2];
                diff |= d ^ cc;
                u64 carry = ~cc;                 // count step s-1 uncovered
                #pragma unroll
                for (int j = 0; j < 5; ++j) { u64 t = cnt[i][j] & carry; cnt[i][j] ^= carry; carry = t; }
                save[i] = d;
                nxt[(r0 + i) * LSTR + w] = d;
            }
            if (diff) chg[s & 1] = 1;
            if (tid == 0) chg[(s + 1) & 1] = 0;
            __syncthreads();
            if (!chg[s & 1]) { Kleft = 20 - s; conv = true; break; }
            u64* t = cur; cur = nxt; nxt = t;
        }
        if (!conv) Kleft = 1;                    // one more inc with ~cov_19
    }

    // ---- add remaining Kleft increments in closed form (mask = uncovered)
    #pragma unroll
    for (int i = 0; i < 3; ++i) {
        const u64 m = ~save[i];
        u64 carry = 0;
        #pragma unroll
        for (int j = 0; j < 5; ++j) {
            const u64 a  = ((Kleft >> j) & 1) ? m : 0;
            const u64 x  = cnt[i][j];
            const u64 s1 = x ^ a;
            const u64 c1 = x & a;
            cnt[i][j] = s1 ^ carry;
            carry = c1 | (s1 & carry);
        }
    }

    // ---- epilogue: planes -> bytes, fuse loss for interior rows
    float acc = 0.f;
    #pragma unroll
    for (int i = 0; i < 3; ++i) {
        const int lr = r0 + i;
        const int gy = y0 - HALO + lr;
        if (lr < HALO || lr >= HALO + SINT || gy >= H_) continue;
        cnt[i][0] |= iso[i];                     // isolated fg: 0 -> 1
        u64 q[8];
        #pragma unroll
        for (int g = 0; g < 8; ++g) {
            u64 x = 0;
            #pragma unroll
            for (int j = 0; j < 5; ++j)
                x |= ((cnt[i][j] >> (8 * g)) & 0xFFULL) << (8 * j);
            u64 t;
            t = (x ^ (x >> 7))  & 0x00AA00AA00AA00AAULL; x ^= t ^ (t << 7);
            t = (x ^ (x >> 14)) & 0x0000CCCC0000CCCCULL; x ^= t ^ (t << 14);
            t = (x ^ (x >> 28)) & 0x00000000F0F0F0F0ULL; x ^= t ^ (t << 28);
            q[g] = x;                            // byte p of q[g] = px g*8+p value
        }
        const float4* pp = (const float4*)(pred + ((size_t)b * C_ + c) * HW_ + gy * W_ + w * 64);
        const float4* dd = (const float4*)(invd + (size_t)b * HW_ + gy * W_ + w * 64);
        #pragma unroll
        for (int k = 0; k < 16; ++k) {
            const float4 v  = pp[k];
            const float4 dv = dd[k];
            const u64 qq = q[k >> 1];
            const int sh = (k & 1) * 32;
            acc = fmaf(__expf(v.x) * dv.x, (float)(unsigned)((qq >> (sh     )) & 0xFF), acc);
            acc = fmaf(__expf(v.y) * dv.y, (float)(unsigned)((qq >> (sh +  8)) & 0xFF), acc);
            acc = fmaf(__expf(v.z) * dv.z, (float)(unsigned)((qq >> (sh + 16)) & 0xFF), acc);
            acc = fmaf(__expf(v.w) * dv.w, (float)(unsigned)((qq >> (sh + 24)) & 0xFF), acc);
        }
    }

    // ---- block reduce + one atomic
    #pragma unroll
    for (int off = 32; off > 0; off >>= 1) acc += __shfl_down(acc, off);
    if ((tid & 63) == 0) part[tid >> 6] = acc;
    __syncthreads();
    if (tid == 0) {
        float s = (part[0] + part[1]) + (part[2] + part[3]);
        atomicAdd(out, s * (1.0f / 39845888.0f));   // / (B*C*H*W)
    }
}

extern "C" void kernel_launch(void* const* d_in, const int* in_sizes, int n_in,
                              void* d_out, int out_size, void* d_ws, size_t ws_size,
                              hipStream_t stream) {
    const float* pred   = (const float*)d_in[0];
    const int*   target = (const int*)d_in[1];
    float* invd = (float*)d_ws;                            // 8,388,608 B
    u64*   masks = (u64*)((char*)d_ws + 8388608);          // 4,980,736 B
    float* out = (float*)d_out;

    hipMemsetAsync(out, 0, sizeof(float), stream);         // harness poisons d_out
    mask_kernel<<<256, 256, 0, stream>>>(target, masks);
    invd_kernel<<<2048, 256, 0, stream>>>(pred, invd);
    sdf_loss_kernel<<<B_ * C_ * NSTRIP, 256, 0, stream>>>(masks, pred, invd, out);
}

// Round 5
// 298.631 us; speedup vs baseline: 1.9494x; 1.0912x over previous
//
#include <hip/hip_runtime.h>

#define B_ 8
#define C_ 19
#define H_ 512
#define W_ 512
#define HW_ (H_*W_)

#define HALO   20
#define SINT   56            // interior rows per strip
#define SROWS  96            // HALO + SINT + HALO
#define NSTRIP 10            // 10*56 = 560 >= 512
#define LSTR   9             // padded LDS row stride in u64

typedef unsigned long long u64;

// ---------- pass A: bit-pack target into per-class masks ---------------------
__global__ __launch_bounds__(256) void mask_kernel(const int* __restrict__ target,
                                                   u64* __restrict__ masks) {
    __shared__ u64 mlds[64][21];
    const int blk  = blockIdx.x;          // 512 blocks, 64 per image
    const int b    = blk >> 6;
    const int base = (blk & 63) * 64;     // first word within image
    const int tid  = threadIdx.x;
    const int lane = tid & 63, wv = tid >> 6;
    const int* tgt = target + b * HW_;
    for (int t = 0; t < 16; ++t) {
        const int cl = wv * 16 + t;       // chunk-local word 0..63
        const int x  = tgt[(base + cl) * 64 + lane];
        u64 keep = 0;
        #pragma unroll
        for (int c = 0; c < C_; ++c) {
            u64 m = __ballot(x == c);
            if (lane == c) keep = m;
        }
        if (lane < C_) mlds[cl][lane] = keep;
    }
    __syncthreads();
    for (int idx = tid; idx < C_ * 64; idx += 256) {
        const int c = idx >> 6, wl = idx & 63;
        masks[((size_t)b * C_ + c) * 4096 + base + wl] = mlds[wl][c];
    }
}

// ---------- pass B: inverse softmax denominator per pixel --------------------
__global__ __launch_bounds__(256) void invd_kernel(const float* __restrict__ pred,
                                                   float* __restrict__ invd) {
    const int t   = blockIdx.x * 256 + threadIdx.x;   // 0..524287
    const int b   = t >> 16;
    const int hw4 = (t & 65535) << 2;
    const float* pbase = pred + (size_t)b * C_ * HW_ + hw4;
    float s0=0.f, s1=0.f, s2=0.f, s3=0.f;
    #pragma unroll
    for (int c = 0; c < C_; ++c) {
        float4 v = *(const float4*)(pbase + (size_t)c * HW_);
        s0 += __expf(v.x); s1 += __expf(v.y); s2 += __expf(v.z); s3 += __expf(v.w);
    }
    float4 o; o.x = 1.0f/s0; o.y = 1.0f/s1; o.z = 1.0f/s2; o.w = 1.0f/s3;
    *(float4*)(invd + (size_t)b * HW_ + hw4) = o;
}

// ---------- pass C: strip dilation (h-rows in LDS) + fused loss --------------
// LDS holds the horizontally-pre-spread rows h = cov | cov<<1 | cov>>1 (+word
// carries). Step: d[r] = h[r-1]|h[r]|h[r+1]; own 3 h-rows in regs -> only 2
// LDS reads + 3 writes per step. First-covered-step recorded into 5 bit-planes
// via nb = d ^ save (monotone coverage); uncovered at end -> 20.
__global__ __launch_bounds__(256) void sdf_loss_kernel(const u64* __restrict__ masks,
                                                       const float* __restrict__ pred,
                                                       const float* __restrict__ invd,
                                                       float* __restrict__ out) {
    __shared__ u64 bufA[SROWS * LSTR];
    __shared__ u64 bufB[SROWS * LSTR];
    __shared__ int chg[2];
    __shared__ float part[4];
    const int blk   = blockIdx.x;            // 0 .. 8*19*10-1
    const int strip = blk % NSTRIP;
    const int bc    = blk / NSTRIP;
    const int b     = bc / C_;
    const int c     = bc - b * C_;
    const int y0    = strip * SINT;          // first interior global row
    const int tid   = threadIdx.x;
    const int w     = tid & 7;               // word column 0..7
    const int r0    = (tid >> 3) * 3;        // first owned local row
    const u64* mk   = masks + ((size_t)b * C_ + c) * 4096;

    if (tid < 2) chg[tid] = 0;

    u64 save[3], hreg[3], iso[3], pl[3][5];
    #pragma unroll
    for (int i = 0; i < 3; ++i) {
        iso[i] = 0;
        #pragma unroll
        for (int j = 0; j < 5; ++j) pl[i][j] = 0;
    }

    // ---- load own mask rows (zero outside image)
    #pragma unroll
    for (int i = 0; i < 3; ++i) {
        const int gy = y0 - HALO + r0 + i;
        save[i] = (gy >= 0 && gy < H_) ? mk[gy * 8 + w] : 0;
    }

    // ---- build h0 (+ keep no-center spread nc for iso detection)
    u64 nc[3];
    {
        unsigned mp = (unsigned)(save[0] >> 63) | ((unsigned)(save[1] >> 63) << 1) | ((unsigned)(save[2] >> 63) << 2);
        unsigned lp = ((unsigned)save[0] & 1) | (((unsigned)save[1] & 1) << 1) | (((unsigned)save[2] & 1) << 2);
        unsigned fl = __shfl_up(mp, 1);   if (w == 0) fl = 0;
        unsigned fr = __shfl_down(lp, 1); if (w == 7) fr = 0;
        #pragma unroll
        for (int i = 0; i < 3; ++i) {
            nc[i]   = (save[i] << 1) | (save[i] >> 1) | (u64)((fl >> i) & 1) | ((u64)((fr >> i) & 1) << 63);
            hreg[i] = nc[i] | save[i];
            bufA[(r0 + i) * LSTR + w] = hreg[i];
        }
    }
    __syncthreads();

    u64* cur = bufA;
    u64* nxt = bufB;
    bool done = false;

    // ---- step 1: exclude-center neighbor set (for iso), then union
    {
        u64 hup = (r0 > 0)          ? cur[(r0 - 1) * LSTR + w] : 0;
        u64 hdn = (r0 + 3 < SROWS)  ? cur[(r0 + 3) * LSTR + w] : 0;
        u64 nbr[3], d[3];
        nbr[0] = nc[0] | hup     | hreg[1];
        nbr[1] = nc[1] | hreg[0] | hreg[2];
        nbr[2] = nc[2] | hreg[1] | hdn;
        u64 diff = 0;
        #pragma unroll
        for (int i = 0; i < 3; ++i) {
            iso[i] = save[i] & ~nbr[i];
            d[i]   = save[i] | nbr[i];
            u64 nb = d[i] ^ save[i];
            pl[i][0] |= nb;                  // step 1 = 0b00001
            diff |= nb;
            save[i] = d[i];
        }
        unsigned mp = (unsigned)(d[0] >> 63) | ((unsigned)(d[1] >> 63) << 1) | ((unsigned)(d[2] >> 63) << 2);
        unsigned lp = ((unsigned)d[0] & 1) | (((unsigned)d[1] & 1) << 1) | (((unsigned)d[2] & 1) << 2);
        unsigned fl = __shfl_up(mp, 1);   if (w == 0) fl = 0;
        unsigned fr = __shfl_down(lp, 1); if (w == 7) fr = 0;
        #pragma unroll
        for (int i = 0; i < 3; ++i) {
            hreg[i] = d[i] | (d[i] << 1) | (d[i] >> 1) | (u64)((fl >> i) & 1) | ((u64)((fr >> i) & 1) << 63);
            nxt[(r0 + i) * LSTR + w] = hreg[i];
        }
        if (diff) chg[1] = 1;
        if (tid == 0) chg[0] = 0;
        __syncthreads();
        if (!chg[1]) done = true;
        else { u64* t = cur; cur = nxt; nxt = t; }
    }

    // ---- steps 2..19: d[r] = h[r-1]|h[r]|h[r+1]; early exit on convergence
    if (!done) {
        #pragma unroll
        for (int s = 2; s <= 19; ++s) {
            u64 hup = (r0 > 0)         ? cur[(r0 - 1) * LSTR + w] : 0;
            u64 hdn = (r0 + 3 < SROWS) ? cur[(r0 + 3) * LSTR + w] : 0;
            u64 d[3];
            d[0] = hup     | hreg[0] | hreg[1];
            d[1] = hreg[0] | hreg[1] | hreg[2];
            d[2] = hreg[1] | hreg[2] | hdn;
            u64 diff = 0;
            #pragma unroll
            for (int i = 0; i < 3; ++i) {
                u64 nb = d[i] ^ save[i];     // newly covered (coverage monotone)
                diff |= nb;
                if (s & 1)  pl[i][0] |= nb;
                if (s & 2)  pl[i][1] |= nb;
                if (s & 4)  pl[i][2] |= nb;
                if (s & 8)  pl[i][3] |= nb;
                if (s & 16) pl[i][4] |= nb;
                save[i] = d[i];
            }
            unsigned mp = (unsigned)(d[0] >> 63) | ((unsigned)(d[1] >> 63) << 1) | ((unsigned)(d[2] >> 63) << 2);
            unsigned lp = ((unsigned)d[0] & 1) | (((unsigned)d[1] & 1) << 1) | (((unsigned)d[2] & 1) << 2);
            unsigned fl = __shfl_up(mp, 1);   if (w == 0) fl = 0;
            unsigned fr = __shfl_down(lp, 1); if (w == 7) fr = 0;
            #pragma unroll
            for (int i = 0; i < 3; ++i) {
                hreg[i] = d[i] | (d[i] << 1) | (d[i] >> 1) | (u64)((fl >> i) & 1) | ((u64)((fr >> i) & 1) << 63);
                nxt[(r0 + i) * LSTR + w] = hreg[i];
            }
            if (diff) chg[s & 1] = 1;
            if (tid == 0) chg[(s + 1) & 1] = 0;
            __syncthreads();
            if (!chg[s & 1]) break;
            u64* t = cur; cur = nxt; nxt = t;
        }
    }

    // ---- epilogue: planes -> bytes, fuse loss for interior rows
    float acc = 0.f;
    #pragma unroll
    for (int i = 0; i < 3; ++i) {
        const int lr = r0 + i;
        const int gy = y0 - HALO + lr;
        if (lr < HALO || lr >= HALO + SINT || gy >= H_) continue;
        pl[i][0] |= iso[i];                  // isolated fg: 0 -> 1
        const u64 m = ~save[i];              // still uncovered -> 20 = 0b10100
        pl[i][2] |= m;
        pl[i][4] |= m;
        u64 q[8];
        #pragma unroll
        for (int g = 0; g < 8; ++g) {
            u64 x = 0;
            #pragma unroll
            for (int j = 0; j < 5; ++j)
                x |= ((pl[i][j] >> (8 * g)) & 0xFFULL) << (8 * j);
            u64 t;
            t = (x ^ (x >> 7))  & 0x00AA00AA00AA00AAULL; x ^= t ^ (t << 7);
            t = (x ^ (x >> 14)) & 0x0000CCCC0000CCCCULL; x ^= t ^ (t << 14);
            t = (x ^ (x >> 28)) & 0x00000000F0F0F0F0ULL; x ^= t ^ (t << 28);
            q[g] = x;                        // byte p of q[g] = px g*8+p value
        }
        const float4* pp = (const float4*)(pred + ((size_t)b * C_ + c) * HW_ + gy * W_ + w * 64);
        const float4* dd = (const float4*)(invd + (size_t)b * HW_ + gy * W_ + w * 64);
        #pragma unroll
        for (int k = 0; k < 16; ++k) {
            const float4 v  = pp[k];
            const float4 dv = dd[k];
            const u64 qq = q[k >> 1];
            const int sh = (k & 1) * 32;
            acc = fmaf(__expf(v.x) * dv.x, (float)(unsigned)((qq >> (sh     )) & 0xFF), acc);
            acc = fmaf(__expf(v.y) * dv.y, (float)(unsigned)((qq >> (sh +  8)) & 0xFF), acc);
            acc = fmaf(__expf(v.z) * dv.z, (float)(unsigned)((qq >> (sh + 16)) & 0xFF), acc);
            acc = fmaf(__expf(v.w) * dv.w, (float)(unsigned)((qq >> (sh + 24)) & 0xFF), acc);
        }
    }

    // ---- block reduce + one atomic
    #pragma unroll
    for (int off = 32; off > 0; off >>= 1) acc += __shfl_down(acc, off);
    if ((tid & 63) == 0) part[tid >> 6] = acc;
    __syncthreads();
    if (tid == 0) {
        float s = (part[0] + part[1]) + (part[2] + part[3]);
        atomicAdd(out, s * (1.0f / 39845888.0f));   // / (B*C*H*W)
    }
}

extern "C" void kernel_launch(void* const* d_in, const int* in_sizes, int n_in,
                              void* d_out, int out_size, void* d_ws, size_t ws_size,
                              hipStream_t stream) {
    const float* pred   = (const float*)d_in[0];
    const int*   target = (const int*)d_in[1];
    float* invd = (float*)d_ws;                            // 8,388,608 B
    u64*   masks = (u64*)((char*)d_ws + 8388608);          // 4,980,736 B
    float* out = (float*)d_out;

    hipMemsetAsync(out, 0, sizeof(float), stream);         // harness poisons d_out
    mask_kernel<<<512, 256, 0, stream>>>(target, masks);
    invd_kernel<<<2048, 256, 0, stream>>>(pred, invd);
    sdf_loss_kernel<<<B_ * C_ * NSTRIP, 256, 0, stream>>>(masks, pred, invd, out);
}

// Round 6
// 277.377 us; speedup vs baseline: 2.0987x; 1.0766x over previous
//
#include <hip/hip_runtime.h>

#define B_ 8
#define C_ 19
#define H_ 512
#define W_ 512
#define HW_ (H_*W_)

#define HALO   20
#define INTR   8             // interior rows per strip
#define WIN    48            // HALO + INTR + HALO
#define NSTRIP 64            // 64*8 = 512

typedef unsigned long long u64;

// ---------- pass A: bit-pack target into per-class masks ---------------------
__global__ __launch_bounds__(256) void mask_kernel(const int* __restrict__ target,
                                                   u64* __restrict__ masks) {
    __shared__ u64 mlds[64][21];
    const int blk  = blockIdx.x;          // 512 blocks, 64 per image
    const int b    = blk >> 6;
    const int base = (blk & 63) * 64;     // first word within image
    const int tid  = threadIdx.x;
    const int lane = tid & 63, wv = tid >> 6;
    const int* tgt = target + b * HW_;
    for (int t = 0; t < 16; ++t) {
        const int cl = wv * 16 + t;       // chunk-local word 0..63
        const int x  = tgt[(base + cl) * 64 + lane];
        u64 keep = 0;
        #pragma unroll
        for (int c = 0; c < C_; ++c) {
            u64 m = __ballot(x == c);
            if (lane == c) keep = m;
        }
        if (lane < C_) mlds[cl][lane] = keep;
    }
    __syncthreads();
    for (int idx = tid; idx < C_ * 64; idx += 256) {
        const int c = idx >> 6, wl = idx & 63;
        masks[((size_t)b * C_ + c) * 4096 + base + wl] = mlds[wl][c];
    }
}

// ---------- pass B: fused per-strip dilation (register-resident, sync-free
// within a wave) + loss. One block per (b, 8-row strip); 4 waves round-robin
// the 19 classes. A wave holds a whole 48x512 class window in registers:
// lane = (rowgroup g = lane>>3) x (word-col w = lane&7), 6 rows/lane.
// Row exchange: __shfl +-8; cross-word carry: __shfl +-1. No LDS, no barriers
// in the 19-step loop; first-covered-step recorded into 5 bit-planes.
// Interior sdf bytes -> LDS; then loss streams pred ONCE (all classes).
__global__ __launch_bounds__(256, 2) void fused_kernel(const u64* __restrict__ masks,
                                                       const float* __restrict__ pred,
                                                       float* __restrict__ out) {
    __shared__ unsigned char sdfl[C_ * INTR * W_];   // 19*8*512 = 77824 B
    __shared__ float part[4];
    const int blk   = blockIdx.x;          // 0..511
    const int strip = blk & 63;
    const int b     = blk >> 6;
    const int tid   = threadIdx.x;
    const int wv    = tid >> 6, lane = tid & 63;
    const int w     = lane & 7, g = lane >> 3;
    const int gytop = strip * INTR - HALO; // global row of window row 0

    for (int c = wv; c < C_; c += 4) {
        const u64* mk = masks + ((size_t)b * C_ + c) * 4096;
        u64 cov[6], h[6], iso[6], pl[6][5];

        // ---- load own 6 mask rows (zero outside image)
        #pragma unroll
        for (int i = 0; i < 6; ++i) {
            const int gy = gytop + g * 6 + i;
            cov[i] = (gy >= 0 && gy < H_) ? mk[gy * 8 + w] : 0;
            iso[i] = 0;
            #pragma unroll
            for (int j = 0; j < 5; ++j) pl[i][j] = 0;
        }

        // ---- build no-center spread nc and full spread h of cov
        u64 nc[6];
        {
            unsigned mp = 0, lp = 0;
            #pragma unroll
            for (int i = 0; i < 6; ++i) {
                mp |= (unsigned)(cov[i] >> 63) << i;
                lp |= ((unsigned)cov[i] & 1) << i;
            }
            unsigned fl = __shfl_up(mp, 1);   if (w == 0) fl = 0;
            unsigned fr = __shfl_down(lp, 1); if (w == 7) fr = 0;
            #pragma unroll
            for (int i = 0; i < 6; ++i) {
                nc[i] = (cov[i] << 1) | (cov[i] >> 1) | (u64)((fl >> i) & 1) | ((u64)((fr >> i) & 1) << 63);
                h[i]  = nc[i] | cov[i];
            }
        }

        // ---- step 1: exclude-center neighbor set (iso), then union
        bool active;
        {
            u64 hup = __shfl_up(h[5], 8);   if (g == 0) hup = 0;
            u64 hdn = __shfl_down(h[0], 8); if (g == 7) hdn = 0;
            u64 d[6], diffw = 0;
            #pragma unroll
            for (int i = 0; i < 6; ++i) {
                const u64 up  = (i > 0) ? h[i - 1] : hup;
                const u64 dn  = (i < 5) ? h[i + 1] : hdn;
                const u64 nbr = nc[i] | up | dn;
                iso[i] = cov[i] & ~nbr;
                const u64 nb = nbr & ~cov[i];
                pl[i][0] = nb;               // step 1 = 0b00001
                d[i] = cov[i] | nbr;
                diffw |= nb;
                cov[i] = d[i];
            }
            // rebuild h from d
            unsigned mp = 0, lp = 0;
            #pragma unroll
            for (int i = 0; i < 6; ++i) {
                mp |= (unsigned)(cov[i] >> 63) << i;
                lp |= ((unsigned)cov[i] & 1) << i;
            }
            unsigned fl = __shfl_up(mp, 1);   if (w == 0) fl = 0;
            unsigned fr = __shfl_down(lp, 1); if (w == 7) fr = 0;
            #pragma unroll
            for (int i = 0; i < 6; ++i)
                h[i] = cov[i] | (cov[i] << 1) | (cov[i] >> 1) | (u64)((fl >> i) & 1) | ((u64)((fr >> i) & 1) << 63);
            active = __any(diffw != 0);
        }

        // ---- steps 2..19: d[r] = h[r-1]|h[r]|h[r+1]; wave-wide early exit
        if (active) {
            #pragma unroll
            for (int s = 2; s <= 19; ++s) {
                u64 hup = __shfl_up(h[5], 8);   if (g == 0) hup = 0;
                u64 hdn = __shfl_down(h[0], 8); if (g == 7) hdn = 0;
                u64 diffw = 0;
                #pragma unroll
                for (int i = 0; i < 6; ++i) {
                    const u64 up = (i > 0) ? h[i - 1] : hup;
                    const u64 dn = (i < 5) ? h[i + 1] : hdn;
                    const u64 d  = up | h[i] | dn;
                    const u64 nb = d ^ cov[i];   // newly covered (monotone)
                    diffw |= nb;
                    if (s & 1)  pl[i][0] |= nb;
                    if (s & 2)  pl[i][1] |= nb;
                    if (s & 4)  pl[i][2] |= nb;
                    if (s & 8)  pl[i][3] |= nb;
                    if (s & 16) pl[i][4] |= nb;
                    cov[i] = d;
                }
                if (!__any(diffw != 0)) break;
                if (s < 19) {
                    unsigned mp = 0, lp = 0;
                    #pragma unroll
                    for (int i = 0; i < 6; ++i) {
                        mp |= (unsigned)(cov[i] >> 63) << i;
                        lp |= ((unsigned)cov[i] & 1) << i;
                    }
                    unsigned fl = __shfl_up(mp, 1);   if (w == 0) fl = 0;
                    unsigned fr = __shfl_down(lp, 1); if (w == 7) fr = 0;
                    #pragma unroll
                    for (int i = 0; i < 6; ++i)
                        h[i] = cov[i] | (cov[i] << 1) | (cov[i] >> 1) | (u64)((fl >> i) & 1) | ((u64)((fr >> i) & 1) << 63);
                }
            }
        }

        // ---- epilogue: interior rows -> bytes -> LDS
        #pragma unroll
        for (int i = 0; i < 6; ++i) {
            const int lr = g * 6 + i;
            if (lr < HALO || lr >= HALO + INTR) continue;
            pl[i][0] |= iso[i];              // isolated fg: 0 -> 1
            const u64 m = ~cov[i];           // never covered -> 20 = 0b10100
            pl[i][2] |= m;
            pl[i][4] |= m;
            u64* dst = (u64*)&sdfl[(c * INTR + (lr - HALO)) * W_ + w * 64];
            #pragma unroll
            for (int g2 = 0; g2 < 8; ++g2) {
                u64 x = 0;
                #pragma unroll
                for (int j = 0; j < 5; ++j)
                    x |= ((pl[i][j] >> (8 * g2)) & 0xFFULL) << (8 * j);
                u64 t;
                t = (x ^ (x >> 7))  & 0x00AA00AA00AA00AAULL; x ^= t ^ (t << 7);
                t = (x ^ (x >> 14)) & 0x0000CCCC0000CCCCULL; x ^= t ^ (t << 14);
                t = (x ^ (x >> 28)) & 0x00000000F0F0F0F0ULL; x ^= t ^ (t << 28);
                dst[g2] = x;                 // byte p = value of pixel g2*8+p
            }
        }
    }
    __syncthreads();

    // ---- loss phase: stream pred once; denominator + numerator together
    float acc = 0.f;
    const float* pb = pred + (size_t)b * C_ * HW_ + (size_t)strip * INTR * W_;
    #pragma unroll
    for (int k = 0; k < 4; ++k) {
        const int p = k * 1024 + tid * 4;    // pixel index within 8x512 tile
        float4 den = {0.f, 0.f, 0.f, 0.f};
        float4 num = {0.f, 0.f, 0.f, 0.f};
        #pragma unroll
        for (int c = 0; c < C_; ++c) {
            const float4 v  = *(const float4*)(pb + (size_t)c * HW_ + p);
            const uchar4 sv = *(const uchar4*)&sdfl[c * 4096 + p];
            const float e0 = __expf(v.x), e1 = __expf(v.y);
            const float e2 = __expf(v.z), e3 = __expf(v.w);
            den.x += e0; den.y += e1; den.z += e2; den.w += e3;
            num.x = fmaf(e0, (float)sv.x, num.x);
            num.y = fmaf(e1, (float)sv.y, num.y);
            num.z = fmaf(e2, (float)sv.z, num.z);
            num.w = fmaf(e3, (float)sv.w, num.w);
        }
        acc += num.x / den.x + num.y / den.y + num.z / den.z + num.w / den.w;
    }

    // ---- block reduce + one atomic
    #pragma unroll
    for (int off = 32; off > 0; off >>= 1) acc += __shfl_down(acc, off);
    if ((tid & 63) == 0) part[tid >> 6] = acc;
    __syncthreads();
    if (tid == 0) {
        float s = (part[0] + part[1]) + (part[2] + part[3]);
        atomicAdd(out, s * (1.0f / 39845888.0f));   // / (B*C*H*W)
    }
}

extern "C" void kernel_launch(void* const* d_in, const int* in_sizes, int n_in,
                              void* d_out, int out_size, void* d_ws, size_t ws_size,
                              hipStream_t stream) {
    const float* pred   = (const float*)d_in[0];
    const int*   target = (const int*)d_in[1];
    u64* masks = (u64*)d_ws;                               // 4,980,736 B
    float* out = (float*)d_out;

    hipMemsetAsync(out, 0, sizeof(float), stream);         // harness poisons d_out
    mask_kernel<<<512, 256, 0, stream>>>(target, masks);
    fused_kernel<<<B_ * NSTRIP, 256, 0, stream>>>(masks, pred, out);
}